// Round 1
// baseline (700.246 us; speedup 1.0000x reference)
//
#include <hip/hip_runtime.h>
#include <math.h>

// NeRF renderer: 4096 rays, 128 coarse + 128 fine samples, tiny MLP field.
// One wave (64 lanes) per ray; lane = sample for MLP eval batches.
// Block = 256 threads = 4 rays. Weights staged in LDS once per block.

#define NS 128   // num_steps (hardcoded per reference setup)
#define US 128   // upsample_steps
#define BOUNDF 2.0f

struct RayLds {
    float zc[128];        // coarse z
    float zf[128];        // fine z (sorted by construction)
    float sgc[128];       // coarse sigma
    float sgf[128];       // fine sigma
    float rgbc[128][3];
    float rgbf[128][3];
    float cdf[128];       // 127 used
    float wc[128];        // coarse alpha -> weights
    float alpha2[256];    // merged alpha -> weights
    unsigned short perm[256];
};

// MLP field eval for one point (per-lane). Weights in LDS:
//   sW1t[j] = {W1[0][j], W1[1][j], W1[2][j], b1[j]}
//   sW2t row j (stride 72): [0..63]=W2[:,j], [64]=b2[j], [65]=Wsig[j], [66..68]=Wrgb[j][0..2]
__device__ __forceinline__ void eval_field(
    float px, float py, float pz,
    const float4* __restrict__ sW1t, const float* __restrict__ sW2t,
    float base_r, float base_g, float base_b,
    float& sigma, float& r, float& g, float& b)
{
    float h1[64];
#pragma unroll
    for (int j = 0; j < 64; ++j) {
        float4 w = sW1t[j];
        float v = fmaf(px, w.x, fmaf(py, w.y, fmaf(pz, w.z, w.w)));
        h1[j] = fmaxf(v, 0.0f);
    }
    float as = 0.0f, a0 = 0.0f, a1 = 0.0f, a2 = 0.0f;
    for (int j = 0; j < 64; ++j) {
        const float* row = sW2t + j * 72;
        float acc = row[64];  // b2[j]
#pragma unroll
        for (int i = 0; i < 64; i += 4) {
            float4 w = *(const float4*)(row + i);
            acc = fmaf(h1[i + 0], w.x, acc);
            acc = fmaf(h1[i + 1], w.y, acc);
            acc = fmaf(h1[i + 2], w.z, acc);
            acc = fmaf(h1[i + 3], w.w, acc);
        }
        float h2 = fmaxf(acc, 0.0f);
        as = fmaf(h2, row[65], as);
        a0 = fmaf(h2, row[66], a0);
        a1 = fmaf(h2, row[67], a1);
        a2 = fmaf(h2, row[68], a2);
    }
    // softplus (stable, matches jax.nn.softplus)
    sigma = fmaxf(as, 0.0f) + log1pf(__expf(-fabsf(as)));
    r = 1.0f / (1.0f + __expf(-(a0 + base_r)));
    g = 1.0f / (1.0f + __expf(-(a1 + base_g)));
    b = 1.0f / (1.0f + __expf(-(a2 + base_b)));
}

__global__ __launch_bounds__(256)
void nerf_kernel(const float* __restrict__ rays_o, const float* __restrict__ rays_d,
                 const float* __restrict__ W1, const float* __restrict__ b1,
                 const float* __restrict__ W2, const float* __restrict__ b2,
                 const float* __restrict__ Wsig, const float* __restrict__ Wrgb,
                 const float* __restrict__ brgb,
                 float* __restrict__ out_depth, float* __restrict__ out_img,
                 int nRays)
{
    __shared__ __align__(16) float4 sW1t[64];
    __shared__ __align__(16) float sW2t[64 * 72];
    __shared__ RayLds rl[4];

    const int tid  = threadIdx.x;
    const int lane = tid & 63;
    const int wv   = tid >> 6;

    // --- stage weights (whole block) ---
    if (tid < 64) {
        sW1t[tid] = make_float4(W1[tid], W1[64 + tid], W1[128 + tid], b1[tid]);
        sW2t[tid * 72 + 64] = b2[tid];
        sW2t[tid * 72 + 65] = Wsig[tid];
        sW2t[tid * 72 + 66] = Wrgb[tid * 3 + 0];
        sW2t[tid * 72 + 67] = Wrgb[tid * 3 + 1];
        sW2t[tid * 72 + 68] = Wrgb[tid * 3 + 2];
    }
    for (int idx = tid; idx < 4096; idx += 256) {
        int i = idx >> 6, j = idx & 63;
        sW2t[j * 72 + i] = W2[i * 64 + j];   // transposed: row j = column j of W2
    }
    __syncthreads();

    int ray = blockIdx.x * 4 + wv;
    bool valid = ray < nRays;
    int rayc = valid ? ray : (nRays - 1);
    RayLds& R = rl[wv];

    const float ox = rays_o[rayc * 3 + 0], oy = rays_o[rayc * 3 + 1], oz = rays_o[rayc * 3 + 2];
    const float dx = rays_d[rayc * 3 + 0], dy = rays_d[rayc * 3 + 1], dzv = rays_d[rayc * 3 + 2];

    // --- near/far vs cube [-2,2]^3 ---
    float t0x = (-BOUNDF - ox) / (dx + 1e-15f), t1x = (BOUNDF - ox) / (dx + 1e-15f);
    float t0y = (-BOUNDF - oy) / (dy + 1e-15f), t1y = (BOUNDF - oy) / (dy + 1e-15f);
    float t0z = (-BOUNDF - oz) / (dzv + 1e-15f), t1z = (BOUNDF - oz) / (dzv + 1e-15f);
    float nearv = fmaxf(fminf(t0x, t1x), fmaxf(fminf(t0y, t1y), fminf(t0z, t1z)));
    float farv  = fminf(fmaxf(t0x, t1x), fminf(fmaxf(t0y, t1y), fmaxf(t0z, t1z)));
    if (farv < nearv) { nearv = 1e9f; farv = 1e9f; }
    nearv = fmaxf(nearv, 0.05f);
    const float span = farv - nearv;
    const float dzc = span * (1.0f / 127.0f);        // coarse spacing
    const float sample_dist = span * (1.0f / 128.0f);

    // per-ray rgb bias: brgb + dirs @ Wrgb[64:67]
    const float base_r = brgb[0] + dx * Wrgb[64 * 3 + 0] + dy * Wrgb[65 * 3 + 0] + dzv * Wrgb[66 * 3 + 0];
    const float base_g = brgb[1] + dx * Wrgb[64 * 3 + 1] + dy * Wrgb[65 * 3 + 1] + dzv * Wrgb[66 * 3 + 1];
    const float base_b = brgb[2] + dx * Wrgb[64 * 3 + 2] + dy * Wrgb[65 * 3 + 2] + dzv * Wrgb[66 * 3 + 2];

    // --- coarse eval: 2 batches of 64 samples ---
    for (int bt = 0; bt < 2; ++bt) {
        int s = bt * 64 + lane;
        float z = fmaf(span, (float)s * (1.0f / 127.0f), nearv);
        R.zc[s] = z;
        float px = fminf(fmaxf(fmaf(dx, z, ox), -BOUNDF), BOUNDF);
        float py = fminf(fmaxf(fmaf(dy, z, oy), -BOUNDF), BOUNDF);
        float pz = fminf(fmaxf(fmaf(dzv, z, oz), -BOUNDF), BOUNDF);
        float sg, cr, cg, cb;
        eval_field(px, py, pz, sW1t, sW2t, base_r, base_g, base_b, sg, cr, cg, cb);
        R.sgc[s] = sg;
        R.rgbc[s][0] = cr; R.rgbc[s][1] = cg; R.rgbc[s][2] = cb;
    }
    __syncthreads();

    // --- coarse alphas ---
    for (int bt = 0; bt < 2; ++bt) {
        int s = bt * 64 + lane;
        float delta = (s < 127) ? (R.zc[s + 1] - R.zc[s]) : sample_dist;
        R.wc[s] = 1.0f - __expf(-delta * R.sgc[s]);   // alpha (temp)
    }
    __syncthreads();
    if (lane == 0) {  // alpha -> weight via transmittance cumprod
        float T = 1.0f;
        for (int k = 0; k < 128; ++k) {
            float a = R.wc[k];
            R.wc[k] = a * T;
            T *= (1.0f - a + 1e-15f);
        }
    }
    __syncthreads();

    // --- pdf/cdf over weights[1:127] (126 values) ---
    float pacc = R.wc[1 + lane] + 1e-5f;
    if (lane < 62) pacc += R.wc[65 + lane] + 1e-5f;
#pragma unroll
    for (int off = 32; off; off >>= 1) pacc += __shfl_xor(pacc, off);
    if (lane == 0) {
        float inv = 1.0f / pacc;
        float run = 0.0f;
        R.cdf[0] = 0.0f;
        for (int m = 0; m < 126; ++m) {
            run += R.wc[1 + m] + 1e-5f;
            R.cdf[1 + m] = run * inv;
        }
    }
    __syncthreads();

    // --- inverse-CDF sampling: 2 u's per lane ---
    for (int bt = 0; bt < 2; ++bt) {
        int i = bt * 64 + lane;
        float u = (float)(2 * i + 1) * (1.0f / 256.0f);
        int lo = 0, hi = 127;   // searchsorted right over cdf[0..126]
        while (lo < hi) { int mid = (lo + hi) >> 1; if (R.cdf[mid] <= u) lo = mid + 1; else hi = mid; }
        int below = max(lo - 1, 0), above = min(lo, 126);
        float cb = R.cdf[below], ca = R.cdf[above];
        float binb = fmaf(dzc, (float)below + 0.5f, nearv);  // z_mid[below]
        float bina = fmaf(dzc, (float)above + 0.5f, nearv);
        float denom = ca - cb;
        if (denom < 1e-5f) denom = 1.0f;
        float t = (u - cb) / denom;
        R.zf[i] = fmaf(t, bina - binb, binb);
    }
    __syncthreads();

    // --- fine eval ---
    for (int bt = 0; bt < 2; ++bt) {
        int s = bt * 64 + lane;
        float z = R.zf[s];
        float px = fminf(fmaxf(fmaf(dx, z, ox), -BOUNDF), BOUNDF);
        float py = fminf(fmaxf(fmaf(dy, z, oy), -BOUNDF), BOUNDF);
        float pz = fminf(fmaxf(fmaf(dzv, z, oz), -BOUNDF), BOUNDF);
        float sg, cr, cg, cb;
        eval_field(px, py, pz, sW1t, sW2t, base_r, base_g, base_b, sg, cr, cg, cb);
        R.sgf[s] = sg;
        R.rgbf[s][0] = cr; R.rgbf[s][1] = cg; R.rgbf[s][2] = cb;
    }
    __syncthreads();

    // --- stable merge of two sorted length-128 lists (merge-path ranks) ---
    for (int bt = 0; bt < 2; ++bt) {
        int k = bt * 64 + lane;
        // coarse element k: rank = k + count(zf < zc[k])
        float v = R.zc[k];
        int lo = 0, hi = 128;
        while (lo < hi) { int mid = (lo + hi) >> 1; if (R.zf[mid] < v) lo = mid + 1; else hi = mid; }
        R.perm[k + lo] = (unsigned short)k;
        // fine element k: rank = k + count(zc <= zf[k])
        float vf = R.zf[k];
        lo = 0; hi = 128;
        while (lo < hi) { int mid = (lo + hi) >> 1; if (R.zc[mid] <= vf) lo = mid + 1; else hi = mid; }
        R.perm[k + lo] = (unsigned short)(128 + k);
    }
    __syncthreads();

    // --- merged alphas ---
    for (int bt = 0; bt < 4; ++bt) {
        int s = bt * 64 + lane;
        int idx = R.perm[s];
        float z = (idx < 128) ? R.zc[idx] : R.zf[idx - 128];
        float delta;
        if (s < 255) {
            int idx2 = R.perm[s + 1];
            float zn = (idx2 < 128) ? R.zc[idx2] : R.zf[idx2 - 128];
            delta = zn - z;
        } else {
            delta = sample_dist;
        }
        float sg = (idx < 128) ? R.sgc[idx] : R.sgf[idx - 128];
        R.alpha2[s] = 1.0f - __expf(-delta * sg);
    }
    __syncthreads();
    if (lane == 0) {
        float T = 1.0f;
        for (int s2 = 0; s2 < 256; ++s2) {
            float a = R.alpha2[s2];
            R.alpha2[s2] = a * T;
            T *= (1.0f - a + 1e-15f);
        }
    }
    __syncthreads();

    // --- final accumulation ---
    const float invspan = 1.0f / span;  // span==0 -> inf; 0*inf = NaN (matches jnp)
    float dacc = 0.0f, racc = 0.0f, gacc = 0.0f, bacc = 0.0f, wacc = 0.0f;
    for (int bt = 0; bt < 4; ++bt) {
        int s = bt * 64 + lane;
        float w = R.alpha2[s];
        int idx = R.perm[s];
        float z = (idx < 128) ? R.zc[idx] : R.zf[idx - 128];
        float oz = (z - nearv) * invspan;
        oz = (oz < 0.0f) ? 0.0f : ((oz > 1.0f) ? 1.0f : oz);  // NaN propagates like jnp.clip
        dacc = fmaf(w, oz, dacc);
        const float* rgb = (idx < 128) ? R.rgbc[idx] : R.rgbf[idx - 128];
        racc = fmaf(w, rgb[0], racc);
        gacc = fmaf(w, rgb[1], gacc);
        bacc = fmaf(w, rgb[2], bacc);
        wacc += w;
    }
#pragma unroll
    for (int off = 32; off; off >>= 1) {
        dacc += __shfl_xor(dacc, off);
        racc += __shfl_xor(racc, off);
        gacc += __shfl_xor(gacc, off);
        bacc += __shfl_xor(bacc, off);
        wacc += __shfl_xor(wacc, off);
    }
    if (lane == 0 && valid) {
        out_depth[ray] = dacc;
        float bg = 1.0f - wacc;
        out_img[ray * 3 + 0] = racc + bg;
        out_img[ray * 3 + 1] = gacc + bg;
        out_img[ray * 3 + 2] = bacc + bg;
    }
}

extern "C" void kernel_launch(void* const* d_in, const int* in_sizes, int n_in,
                              void* d_out, int out_size, void* d_ws, size_t ws_size,
                              hipStream_t stream) {
    const float* rays_o = (const float*)d_in[0];
    const float* rays_d = (const float*)d_in[1];
    const float* W1   = (const float*)d_in[2];
    const float* b1   = (const float*)d_in[3];
    const float* W2   = (const float*)d_in[4];
    const float* b2   = (const float*)d_in[5];
    const float* Wsig = (const float*)d_in[6];
    const float* Wrgb = (const float*)d_in[7];
    const float* brgb = (const float*)d_in[8];
    // d_in[9]/d_in[10]: num_steps / upsample_steps == 128/128, hardcoded.

    int N = in_sizes[0] / 3;          // 4096 rays
    float* out = (float*)d_out;
    float* out_depth = out;           // [N]
    float* out_img   = out + N;       // [N,3]

    int blocks = (N + 3) / 4;
    nerf_kernel<<<dim3(blocks), dim3(256), 0, stream>>>(
        rays_o, rays_d, W1, b1, W2, b2, Wsig, Wrgb, brgb,
        out_depth, out_img, N);
}

// Round 2
// 321.303 us; speedup vs baseline: 2.1794x; 2.1794x over previous
//
#include <hip/hip_runtime.h>
#include <math.h>

// NeRF renderer: 4096 rays, 128 coarse + 128 fine samples, tiny MLP field.
// One wave (64 lanes) per ray, 2 samples per lane in MLP evals.
// Block = 256 threads = 4 rays. Weights staged in LDS once per block.
// All per-ray scans are wave-parallel (shuffle prefix ops) — no serial lane-0
// loops, no per-ray __syncthreads (per-ray LDS is wave-private; DS ops are
// in-order within a wave).

#define BOUNDF 2.0f

struct RayLds {
    float zc[128];        // coarse z
    float zf[128];        // fine z (sorted by construction)
    float sgc[128];       // coarse sigma
    float sgf[128];       // fine sigma
    float rgbc[128][3];
    float rgbf[128][3];
    float cdf[128];       // 127 used
    float scr[128];       // alphas -> weights scratch
    unsigned short perm[256];
};

__device__ __forceinline__ float sigmoidf(float x) { return 1.0f / (1.0f + __expf(-x)); }

__device__ __forceinline__ float scan_incl_mul(float p, int lane) {
#pragma unroll
    for (int off = 1; off < 64; off <<= 1) {
        float t = __shfl_up(p, off, 64);
        if (lane >= off) p *= t;
    }
    return p;
}

__device__ __forceinline__ float scan_incl_add(float p, int lane) {
#pragma unroll
    for (int off = 1; off < 64; off <<= 1) {
        float t = __shfl_up(p, off, 64);
        if (lane >= off) p += t;
    }
    return p;
}

// MLP field eval for TWO points per lane. Weights in LDS:
//   sW1t[j] = {W1[0][j], W1[1][j], W1[2][j], b1[j]}
//   sW2t row j (stride 72): [0..63]=W2[:,j], [64..67]={Wsig[j],Wrgb[j][0..2]}, [68]=b2[j]
__device__ __forceinline__ void eval_field2(
    float px0, float py0, float pz0, float px1, float py1, float pz1,
    const float4* __restrict__ sW1t, const float* __restrict__ sW2t,
    float base_r, float base_g, float base_b,
    float& sg0, float& r0, float& g0, float& b0,
    float& sg1, float& r1, float& g1, float& b1)
{
    float h1a[64], h1b[64];
#pragma unroll
    for (int j = 0; j < 64; ++j) {
        float4 w = sW1t[j];
        h1a[j] = fmaxf(fmaf(px0, w.x, fmaf(py0, w.y, fmaf(pz0, w.z, w.w))), 0.0f);
        h1b[j] = fmaxf(fmaf(px1, w.x, fmaf(py1, w.y, fmaf(pz1, w.z, w.w))), 0.0f);
    }
    float as0 = 0.f, c00 = 0.f, c10 = 0.f, c20 = 0.f;
    float as1 = 0.f, c01 = 0.f, c11 = 0.f, c21 = 0.f;
#pragma unroll 4
    for (int j = 0; j < 64; ++j) {
        const float* row = sW2t + j * 72;
        float bj = row[68];
        float acc0 = bj, acc1 = bj;
#pragma unroll
        for (int i = 0; i < 64; i += 4) {
            float4 w = *(const float4*)(row + i);
            acc0 = fmaf(h1a[i + 0], w.x, acc0);
            acc0 = fmaf(h1a[i + 1], w.y, acc0);
            acc0 = fmaf(h1a[i + 2], w.z, acc0);
            acc0 = fmaf(h1a[i + 3], w.w, acc0);
            acc1 = fmaf(h1b[i + 0], w.x, acc1);
            acc1 = fmaf(h1b[i + 1], w.y, acc1);
            acc1 = fmaf(h1b[i + 2], w.z, acc1);
            acc1 = fmaf(h1b[i + 3], w.w, acc1);
        }
        float h20 = fmaxf(acc0, 0.0f), h21 = fmaxf(acc1, 0.0f);
        float4 hd = *(const float4*)(row + 64);   // Wsig, Wrgb0, Wrgb1, Wrgb2
        as0 = fmaf(h20, hd.x, as0); c00 = fmaf(h20, hd.y, c00);
        c10 = fmaf(h20, hd.z, c10); c20 = fmaf(h20, hd.w, c20);
        as1 = fmaf(h21, hd.x, as1); c01 = fmaf(h21, hd.y, c01);
        c11 = fmaf(h21, hd.z, c11); c21 = fmaf(h21, hd.w, c21);
    }
    sg0 = fmaxf(as0, 0.0f) + log1pf(__expf(-fabsf(as0)));
    sg1 = fmaxf(as1, 0.0f) + log1pf(__expf(-fabsf(as1)));
    r0 = sigmoidf(c00 + base_r); g0 = sigmoidf(c10 + base_g); b0 = sigmoidf(c20 + base_b);
    r1 = sigmoidf(c01 + base_r); g1 = sigmoidf(c11 + base_g); b1 = sigmoidf(c21 + base_b);
}

__global__ __launch_bounds__(256, 2)
void nerf_kernel(const float* __restrict__ rays_o, const float* __restrict__ rays_d,
                 const float* __restrict__ W1, const float* __restrict__ b1,
                 const float* __restrict__ W2, const float* __restrict__ b2,
                 const float* __restrict__ Wsig, const float* __restrict__ Wrgb,
                 const float* __restrict__ brgb,
                 float* __restrict__ out_depth, float* __restrict__ out_img,
                 int nRays)
{
    __shared__ __align__(16) float4 sW1t[64];
    __shared__ __align__(16) float sW2t[64 * 72];
    __shared__ RayLds rl[4];

    const int tid  = threadIdx.x;
    const int lane = tid & 63;
    const int wv   = tid >> 6;

    // --- stage weights (whole block) ---
    if (tid < 64) {
        sW1t[tid] = make_float4(W1[tid], W1[64 + tid], W1[128 + tid], b1[tid]);
        sW2t[tid * 72 + 64] = Wsig[tid];
        sW2t[tid * 72 + 65] = Wrgb[tid * 3 + 0];
        sW2t[tid * 72 + 66] = Wrgb[tid * 3 + 1];
        sW2t[tid * 72 + 67] = Wrgb[tid * 3 + 2];
        sW2t[tid * 72 + 68] = b2[tid];
    }
    for (int idx = tid; idx < 4096; idx += 256) {
        int i = idx >> 6, j = idx & 63;
        sW2t[j * 72 + i] = W2[i * 64 + j];   // transposed: row j = column j of W2
    }
    __syncthreads();

    int ray = blockIdx.x * 4 + wv;
    bool valid = ray < nRays;
    int rayc = valid ? ray : (nRays - 1);
    RayLds& R = rl[wv];

    const float ox = rays_o[rayc * 3 + 0], oy = rays_o[rayc * 3 + 1], oz = rays_o[rayc * 3 + 2];
    const float dx = rays_d[rayc * 3 + 0], dy = rays_d[rayc * 3 + 1], dzv = rays_d[rayc * 3 + 2];

    // --- near/far vs cube [-2,2]^3 ---
    float t0x = (-BOUNDF - ox) / (dx + 1e-15f), t1x = (BOUNDF - ox) / (dx + 1e-15f);
    float t0y = (-BOUNDF - oy) / (dy + 1e-15f), t1y = (BOUNDF - oy) / (dy + 1e-15f);
    float t0z = (-BOUNDF - oz) / (dzv + 1e-15f), t1z = (BOUNDF - oz) / (dzv + 1e-15f);
    float nearv = fmaxf(fminf(t0x, t1x), fmaxf(fminf(t0y, t1y), fminf(t0z, t1z)));
    float farv  = fminf(fmaxf(t0x, t1x), fminf(fmaxf(t0y, t1y), fmaxf(t0z, t1z)));
    if (farv < nearv) { nearv = 1e9f; farv = 1e9f; }
    nearv = fmaxf(nearv, 0.05f);
    const float span = farv - nearv;
    const float dzc = span * (1.0f / 127.0f);
    const float sample_dist = span * (1.0f / 128.0f);

    // per-ray rgb bias: brgb + dirs @ Wrgb[64:67]
    const float base_r = brgb[0] + dx * Wrgb[64 * 3 + 0] + dy * Wrgb[65 * 3 + 0] + dzv * Wrgb[66 * 3 + 0];
    const float base_g = brgb[1] + dx * Wrgb[64 * 3 + 1] + dy * Wrgb[65 * 3 + 1] + dzv * Wrgb[66 * 3 + 1];
    const float base_b = brgb[2] + dx * Wrgb[64 * 3 + 2] + dy * Wrgb[65 * 3 + 2] + dzv * Wrgb[66 * 3 + 2];

    const int s0 = lane, s1 = lane + 64;

    // --- coarse eval: samples s0, s1 per lane ---
    float z0 = fmaf(span, (float)s0 * (1.0f / 127.0f), nearv);
    float z1 = fmaf(span, (float)s1 * (1.0f / 127.0f), nearv);
    R.zc[s0] = z0; R.zc[s1] = z1;
    {
        float px0 = fminf(fmaxf(fmaf(dx, z0, ox), -BOUNDF), BOUNDF);
        float py0 = fminf(fmaxf(fmaf(dy, z0, oy), -BOUNDF), BOUNDF);
        float pz0 = fminf(fmaxf(fmaf(dzv, z0, oz), -BOUNDF), BOUNDF);
        float px1 = fminf(fmaxf(fmaf(dx, z1, ox), -BOUNDF), BOUNDF);
        float py1 = fminf(fmaxf(fmaf(dy, z1, oy), -BOUNDF), BOUNDF);
        float pz1 = fminf(fmaxf(fmaf(dzv, z1, oz), -BOUNDF), BOUNDF);
        float sg0, r0, g0, b0, sg1, r1, g1, b1;
        eval_field2(px0, py0, pz0, px1, py1, pz1, sW1t, sW2t,
                    base_r, base_g, base_b, sg0, r0, g0, b0, sg1, r1, g1, b1);
        R.sgc[s0] = sg0; R.rgbc[s0][0] = r0; R.rgbc[s0][1] = g0; R.rgbc[s0][2] = b0;
        R.sgc[s1] = sg1; R.rgbc[s1][0] = r1; R.rgbc[s1][1] = g1; R.rgbc[s1][2] = b1;

        // coarse alphas (deltas from actual z values, matching reference)
        float zn0 = R.zc[s0 + 1];                       // s0+1 <= 64, in-bounds
        int   sn1 = (s1 < 127) ? s1 + 1 : 127;
        float zn1 = R.zc[sn1];
        float d0 = zn0 - z0;
        float d1 = (s1 < 127) ? (zn1 - z1) : sample_dist;
        R.scr[s0] = 1.0f - __expf(-d0 * sg0);
        R.scr[s1] = 1.0f - __expf(-d1 * sg1);
    }

    // --- wave-parallel cumprod: weights for elements 2l, 2l+1 ---
    {
        float aa = R.scr[2 * lane], ab = R.scr[2 * lane + 1];
        float ma = 1.0f - aa + 1e-15f, mb = 1.0f - ab + 1e-15f;
        float p = scan_incl_mul(ma * mb, lane);
        float T0 = __shfl_up(p, 1, 64);
        if (lane == 0) T0 = 1.0f;
        R.scr[2 * lane]     = aa * T0;
        R.scr[2 * lane + 1] = ab * (T0 * ma);
    }

    // --- wave-parallel CDF over pdf[m]=w[1+m]+1e-5, m=0..125 ---
    {
        float pA = 0.f, pB = 0.f;
        if (lane < 63) {
            pA = R.scr[2 * lane + 1] + 1e-5f;
            pB = R.scr[2 * lane + 2] + 1e-5f;
        }
        float S = scan_incl_add(pA + pB, lane);
        float total = __shfl(S, 63, 64);
        float sexcl = __shfl_up(S, 1, 64);
        if (lane == 0) sexcl = 0.f;
        float inv = 1.0f / total;
        if (lane == 63) {
            R.cdf[0] = 0.0f;
        } else {
            R.cdf[1 + 2 * lane] = (sexcl + pA) * inv;
            R.cdf[2 + 2 * lane] = (sexcl + pA + pB) * inv;
        }
    }

    // --- inverse-CDF sampling: i0=lane, i1=lane+64 ---
#pragma unroll
    for (int bt = 0; bt < 2; ++bt) {
        int i = bt * 64 + lane;
        float u = (float)(2 * i + 1) * (1.0f / 256.0f);
        int lo = 0, hi = 127;   // searchsorted right over cdf[0..126]
        while (lo < hi) { int mid = (lo + hi) >> 1; if (R.cdf[mid] <= u) lo = mid + 1; else hi = mid; }
        int below = max(lo - 1, 0), above = min(lo, 126);
        float cb = R.cdf[below], ca = R.cdf[above];
        float binb = fmaf(dzc, (float)below + 0.5f, nearv);
        float bina = fmaf(dzc, (float)above + 0.5f, nearv);
        float denom = ca - cb;
        if (denom < 1e-5f) denom = 1.0f;
        float t = (u - cb) / denom;
        R.zf[i] = fmaf(t, bina - binb, binb);
    }

    // --- fine eval: samples s0, s1 per lane ---
    {
        float zf0 = R.zf[s0], zf1 = R.zf[s1];
        float px0 = fminf(fmaxf(fmaf(dx, zf0, ox), -BOUNDF), BOUNDF);
        float py0 = fminf(fmaxf(fmaf(dy, zf0, oy), -BOUNDF), BOUNDF);
        float pz0 = fminf(fmaxf(fmaf(dzv, zf0, oz), -BOUNDF), BOUNDF);
        float px1 = fminf(fmaxf(fmaf(dx, zf1, ox), -BOUNDF), BOUNDF);
        float py1 = fminf(fmaxf(fmaf(dy, zf1, oy), -BOUNDF), BOUNDF);
        float pz1 = fminf(fmaxf(fmaf(dzv, zf1, oz), -BOUNDF), BOUNDF);
        float sg0, r0, g0, b0, sg1, r1, g1, b1;
        eval_field2(px0, py0, pz0, px1, py1, pz1, sW1t, sW2t,
                    base_r, base_g, base_b, sg0, r0, g0, b0, sg1, r1, g1, b1);
        R.sgf[s0] = sg0; R.rgbf[s0][0] = r0; R.rgbf[s0][1] = g0; R.rgbf[s0][2] = b0;
        R.sgf[s1] = sg1; R.rgbf[s1][0] = r1; R.rgbf[s1][1] = g1; R.rgbf[s1][2] = b1;
    }

    // --- stable merge of two sorted length-128 lists (merge-path ranks) ---
#pragma unroll
    for (int bt = 0; bt < 2; ++bt) {
        int k = bt * 64 + lane;
        float v = R.zc[k];
        int lo = 0, hi = 128;
        while (lo < hi) { int mid = (lo + hi) >> 1; if (R.zf[mid] < v) lo = mid + 1; else hi = mid; }
        R.perm[k + lo] = (unsigned short)k;
        float vf = R.zf[k];
        lo = 0; hi = 128;
        while (lo < hi) { int mid = (lo + hi) >> 1; if (R.zc[mid] <= vf) lo = mid + 1; else hi = mid; }
        R.perm[k + lo] = (unsigned short)(128 + k);
    }

    // --- merged composite: 4 samples per lane, scan + accumulate in regs ---
    {
        int sb = 4 * lane;
        int idxk[4]; float zk[4], sgk[4];
#pragma unroll
        for (int k = 0; k < 4; ++k) {
            int idx = R.perm[sb + k];
            idxk[k] = idx;
            zk[k]  = (idx < 128) ? R.zc[idx]  : R.zf[idx - 128];
            sgk[k] = (idx < 128) ? R.sgc[idx] : R.sgf[idx - 128];
        }
        float znext = __shfl_down(zk[0], 1, 64);   // z of sample 4l+4
        float d0 = zk[1] - zk[0];
        float d1 = zk[2] - zk[1];
        float d2 = zk[3] - zk[2];
        float d3 = (lane < 63) ? (znext - zk[3]) : sample_dist;
        float a0 = 1.0f - __expf(-d0 * sgk[0]);
        float a1 = 1.0f - __expf(-d1 * sgk[1]);
        float a2 = 1.0f - __expf(-d2 * sgk[2]);
        float a3 = 1.0f - __expf(-d3 * sgk[3]);
        float m0 = 1.0f - a0 + 1e-15f, m1 = 1.0f - a1 + 1e-15f;
        float m2 = 1.0f - a2 + 1e-15f, m3 = 1.0f - a3 + 1e-15f;
        float p = scan_incl_mul((m0 * m1) * (m2 * m3), lane);
        float T = __shfl_up(p, 1, 64);
        if (lane == 0) T = 1.0f;

        const float invspan = 1.0f / span;  // span==0 -> inf; 0*inf = NaN (matches jnp)
        float dacc = 0.f, racc = 0.f, gacc = 0.f, bacc = 0.f, wacc = 0.f;
        float aarr[4] = {a0, a1, a2, a3};
        float marr[4] = {m0, m1, m2, m3};
#pragma unroll
        for (int k = 0; k < 4; ++k) {
            float w = aarr[k] * T;
            float ozv = (zk[k] - nearv) * invspan;
            ozv = (ozv < 0.0f) ? 0.0f : ((ozv > 1.0f) ? 1.0f : ozv);  // NaN propagates
            dacc = fmaf(w, ozv, dacc);
            const float* rgb = (idxk[k] < 128) ? R.rgbc[idxk[k]] : R.rgbf[idxk[k] - 128];
            racc = fmaf(w, rgb[0], racc);
            gacc = fmaf(w, rgb[1], gacc);
            bacc = fmaf(w, rgb[2], bacc);
            wacc += w;
            T *= marr[k];
        }
#pragma unroll
        for (int off = 32; off; off >>= 1) {
            dacc += __shfl_xor(dacc, off);
            racc += __shfl_xor(racc, off);
            gacc += __shfl_xor(gacc, off);
            bacc += __shfl_xor(bacc, off);
            wacc += __shfl_xor(wacc, off);
        }
        if (lane == 0 && valid) {
            out_depth[ray] = dacc;
            float bg = 1.0f - wacc;
            out_img[ray * 3 + 0] = racc + bg;
            out_img[ray * 3 + 1] = gacc + bg;
            out_img[ray * 3 + 2] = bacc + bg;
        }
    }
}

extern "C" void kernel_launch(void* const* d_in, const int* in_sizes, int n_in,
                              void* d_out, int out_size, void* d_ws, size_t ws_size,
                              hipStream_t stream) {
    const float* rays_o = (const float*)d_in[0];
    const float* rays_d = (const float*)d_in[1];
    const float* W1   = (const float*)d_in[2];
    const float* b1   = (const float*)d_in[3];
    const float* W2   = (const float*)d_in[4];
    const float* b2   = (const float*)d_in[5];
    const float* Wsig = (const float*)d_in[6];
    const float* Wrgb = (const float*)d_in[7];
    const float* brgb = (const float*)d_in[8];

    int N = in_sizes[0] / 3;          // 4096 rays
    float* out = (float*)d_out;
    float* out_depth = out;           // [N]
    float* out_img   = out + N;       // [N,3]

    int blocks = (N + 3) / 4;
    nerf_kernel<<<dim3(blocks), dim3(256), 0, stream>>>(
        rays_o, rays_d, W1, b1, W2, b2, Wsig, Wrgb, brgb,
        out_depth, out_img, N);
}